// Round 3
// baseline (1049.123 us; speedup 1.0000x reference)
//
#include <hip/hip_runtime.h>
#include <hip/hip_bf16.h>
#include <math.h>

#define N_NODES 50000
#define F_IN 256
#define H1 128
#define C_OUT 40
#define L1W 384   // 3*H1
#define L2W 120   // 3*C_OUT

// ---------------- edge-index dtype detection + normalization ----------------
// Values are < 50000, so if int64, every high word of each 8-byte element is 0.
// If int32, the odd int32 slots are src[2e+1] which are ~never all zero.

__global__ void detect_k(const int* __restrict__ ei, int* __restrict__ flag) {
    __shared__ int any;
    if (threadIdx.x == 0) any = 0;
    __syncthreads();
    int v = 0;
    for (int r = 0; r < 4; r++) {
        int e = threadIdx.x + r * 256;           // pair index
        v |= ei[e * 2 + 1];                       // high word if int64
    }
    if (v != 0) atomicOr(&any, 1);
    __syncthreads();
    if (threadIdx.x == 0) *flag = any;            // 1 => int32 layout, 0 => int64
}

__global__ void conv_k(const int* __restrict__ ei, const int* __restrict__ flag,
                       int* __restrict__ srcN, int* __restrict__ dstN, int E) {
    int e = blockIdx.x * 256 + threadIdx.x;
    if (e >= E) return;
    if (*flag) {
        srcN[e] = ei[e];
        dstN[e] = ei[E + e];
    } else {
        const long long* e64 = (const long long*)ei;
        srcN[e] = (int)e64[e];
        dstN[e] = (int)e64[E + e];
    }
}

// ---------------- CSR build ----------------

__global__ void hist_k(const int* __restrict__ dst, int* __restrict__ cnt, int E) {
    int e = blockIdx.x * 256 + threadIdx.x;
    if (e < E) atomicAdd(&cnt[dst[e]], 1);
}

__global__ void dinv_k(const int* __restrict__ cnt, float* __restrict__ dinv, int n) {
    int i = blockIdx.x * 256 + threadIdx.x;
    if (i < n) dinv[i] = rsqrtf((float)cnt[i] + 1.0f);
}

// single-block exclusive scan over cnt[0..n) -> rowptr[0..n], fill[0..n)
__global__ __launch_bounds__(1024) void scan_k(const int* __restrict__ cnt,
                                               int* __restrict__ rowptr,
                                               int* __restrict__ fill, int n) {
    __shared__ int sums[1024];
    int t = threadIdx.x;
    int per = (n + 1023) / 1024;
    int start = t * per;
    int end = min(start + per, n);
    int s = 0;
    for (int i = start; i < end; i++) s += cnt[i];
    sums[t] = s;
    __syncthreads();
    for (int off = 1; off < 1024; off <<= 1) {
        int v = 0;
        if (t >= off) v = sums[t - off];
        __syncthreads();
        if (t >= off) sums[t] += v;
        __syncthreads();
    }
    int run = sums[t] - s;  // exclusive prefix for this thread's segment
    for (int i = start; i < end; i++) {
        rowptr[i] = run;
        fill[i] = run;
        run += cnt[i];
    }
    if (t == 1023) rowptr[n] = sums[1023];
}

__global__ void scatter_k(const int* __restrict__ srcI, const int* __restrict__ dstI,
                          int* __restrict__ fill, int* __restrict__ csr_src,
                          float* __restrict__ csr_w, const float* __restrict__ dinv, int E) {
    int e = blockIdx.x * 256 + threadIdx.x;
    if (e >= E) return;
    int s = srcI[e], d = dstI[e];
    int pos = atomicAdd(&fill[d], 1);
    csr_src[pos] = s;
    csr_w[pos] = dinv[s] * dinv[d];
}

// ---------------- weight packing ----------------

__global__ void pack1_k(const float* __restrict__ w0, const float* __restrict__ w1,
                        const float* __restrict__ w2, float* __restrict__ wcat) {
    int idx = blockIdx.x * 256 + threadIdx.x;
    if (idx >= F_IN * L1W) return;
    int k = idx / L1W, j = idx % L1W;
    int p = j >> 7, c = j & 127;
    const float* w = (p == 0) ? w0 : (p == 1) ? w1 : w2;
    wcat[idx] = w[k * H1 + c];
}

__global__ void pack2_k(const float* __restrict__ w0, const float* __restrict__ w1,
                        const float* __restrict__ w2, float* __restrict__ wcat) {
    int idx = blockIdx.x * 256 + threadIdx.x;
    if (idx >= L1W * L2W) return;
    int k = idx / L2W, j = idx % L2W;
    int p = j / 40, c = j % 40;
    const float* w = (p == 0) ? w0 : (p == 1) ? w1 : w2;
    wcat[idx] = w[k * C_OUT + c];
}

// ---------------- fp32 tiled GEMM: C[NxM] = A[NxK] @ B[KxM] ----------------
// BM=BN=64, BK=16, 256 threads, 4x4 per thread

__global__ __launch_bounds__(256) void gemm_k(const float* __restrict__ A,
                                              const float* __restrict__ B,
                                              float* __restrict__ C,
                                              int N, int K, int M) {
    __shared__ float As[16][65];
    __shared__ float Bs[16][65];
    int tid = threadIdx.x;
    int rowBase = blockIdx.x * 64;
    int colBase = blockIdx.y * 64;
    int ty = tid >> 4, tx = tid & 15;
    float acc[4][4] = {};
    for (int k0 = 0; k0 < K; k0 += 16) {
        for (int l = tid; l < 64 * 16; l += 256) {
            int r = l >> 4, kk = l & 15;
            int row = rowBase + r;
            As[kk][r] = (row < N) ? A[(size_t)row * K + k0 + kk] : 0.f;
        }
        for (int l = tid; l < 16 * 64; l += 256) {
            int kk = l >> 6, c = l & 63;
            int col = colBase + c;
            Bs[kk][c] = (col < M) ? B[(size_t)(k0 + kk) * M + col] : 0.f;
        }
        __syncthreads();
#pragma unroll
        for (int kk = 0; kk < 16; kk++) {
            float a[4], b[4];
#pragma unroll
            for (int i = 0; i < 4; i++) a[i] = As[kk][ty * 4 + i];
#pragma unroll
            for (int j = 0; j < 4; j++) b[j] = Bs[kk][tx * 4 + j];
#pragma unroll
            for (int i = 0; i < 4; i++)
#pragma unroll
                for (int j = 0; j < 4; j++) acc[i][j] = fmaf(a[i], b[j], acc[i][j]);
        }
        __syncthreads();
    }
    for (int i = 0; i < 4; i++) {
        int row = rowBase + ty * 4 + i;
        if (row >= N) continue;
        for (int j = 0; j < 4; j++) {
            int col = colBase + tx * 4 + j;
            if (col < M) C[(size_t)row * M + col] = acc[i][j];
        }
    }
}

// ---------------- propagation (SpMM by dst, CSR), self-loop fused ----------------

template <int WIDTH>
__global__ void prop_k(const float* __restrict__ src, int slds, int soff,
                       float* __restrict__ dst, int dlds, int doff,
                       const int* __restrict__ rowptr, const int* __restrict__ csr_src,
                       const float* __restrict__ csr_w, const float* __restrict__ dinv,
                       int n) {
    int i = blockIdx.x;
    if (i >= n) return;
    int j = threadIdx.x;
    int beg = rowptr[i], end = rowptr[i + 1];
    float di = dinv[i];
    float acc = 0.f;
    if (j < WIDTH) acc = di * di * src[(size_t)i * slds + soff + j];
    int k = beg;
    for (; k + 1 < end; k += 2) {
        int s0 = csr_src[k], s1 = csr_src[k + 1];
        float w0 = csr_w[k], w1 = csr_w[k + 1];
        if (j < WIDTH) {
            float a = src[(size_t)s0 * slds + soff + j];
            float b = src[(size_t)s1 * slds + soff + j];
            acc = fmaf(w0, a, acc);
            acc = fmaf(w1, b, acc);
        }
    }
    if (k < end) {
        int s0 = csr_src[k];
        float w0 = csr_w[k];
        if (j < WIDTH) acc = fmaf(w0, src[(size_t)s0 * slds + soff + j], acc);
    }
    if (j < WIDTH) dst[(size_t)i * dlds + doff + j] = acc;
}

// ---------------- bias + relu, assembling h in place in Y ----------------
// cols [0,128): y0 (in Y)  [128,256): z1 (in T)  [256,384): z2 (in Y)

__global__ void bias_relu_k(float* __restrict__ Y, const float* __restrict__ T,
                            const float* __restrict__ b1, int n) {
    int idx = blockIdx.x * 256 + threadIdx.x;
    if (idx >= n * L1W) return;
    int j = idx % L1W;
    int i = idx / L1W;
    float v = (j >= 128 && j < 256) ? T[i * 128 + (j - 128)] : Y[idx];
    Y[idx] = fmaxf(v + b1[j], 0.f);
}

// ---------------- log_softmax epilogue ----------------
// column j of logits: j<40 -> U[i,j] (no prop); 40<=j<80 -> T2a[i,j-40] (P once);
// 80<=j<120 -> U[i,j] (P twice, written back into U); + b2[j]

__global__ __launch_bounds__(256) void lsm_k(const float* __restrict__ U,
                                             const float* __restrict__ T2a,
                                             const float* __restrict__ b2,
                                             float* __restrict__ out, int n) {
    int wave = threadIdx.x >> 6;
    int lane = threadIdx.x & 63;
    int i = blockIdx.x * 4 + wave;
    if (i >= n) return;
    float v0, v1;
    {
        int j = lane;  // 0..63
        float v = (j >= 40) ? T2a[i * 40 + (j - 40)] : U[i * 120 + j];
        v0 = v + b2[j];
    }
    if (lane + 64 < 120) {
        int j = lane + 64;  // 64..119
        // BUGFIX (round 2): columns 64..79 belong to the propagated branch -> T2a
        float v = (j < 80) ? T2a[i * 40 + (j - 40)] : U[i * 120 + j];
        v1 = v + b2[j];
    } else {
        v1 = -INFINITY;
    }
    float m = fmaxf(v0, v1);
    for (int off = 32; off; off >>= 1) m = fmaxf(m, __shfl_xor(m, off, 64));
    float s = expf(v0 - m) + ((lane + 64 < 120) ? expf(v1 - m) : 0.f);
    for (int off = 32; off; off >>= 1) s += __shfl_xor(s, off, 64);
    float ls = logf(s) + m;
    out[i * 120 + lane] = v0 - ls;
    if (lane + 64 < 120) out[i * 120 + lane + 64] = v1 - ls;
}

// ---------------- launch ----------------

static inline size_t align256(size_t x) { return (x + 255) & ~(size_t)255; }

extern "C" void kernel_launch(void* const* d_in, const int* in_sizes, int n_in,
                              void* d_out, int out_size, void* d_ws, size_t ws_size,
                              hipStream_t stream) {
    const float* x = (const float*)d_in[0];
    const int* ei = (const int*)d_in[1];
    const float* W1_0 = (const float*)d_in[2];
    const float* W1_1 = (const float*)d_in[3];
    const float* W1_2 = (const float*)d_in[4];
    const float* b1 = (const float*)d_in[5];
    const float* W2_0 = (const float*)d_in[6];
    const float* W2_1 = (const float*)d_in[7];
    const float* W2_2 = (const float*)d_in[8];
    const float* b2 = (const float*)d_in[9];
    float* out = (float*)d_out;

    const int n = N_NODES;
    const int E = in_sizes[1] / 2;

    // workspace carve-up
    char* p = (char*)d_ws;
    size_t off = 0;
    auto alloc = [&](size_t bytes) {
        void* r = p + off;
        off = align256(off + bytes);
        return r;
    };
    int* flag = (int*)alloc(4);
    int* srcN = (int*)alloc((size_t)E * 4);
    int* dstN = (int*)alloc((size_t)E * 4);
    int* cnt = (int*)alloc((size_t)n * 4);
    int* rowptr = (int*)alloc((size_t)(n + 1) * 4);
    int* fill = (int*)alloc((size_t)n * 4);
    float* dinv = (float*)alloc((size_t)n * 4);
    int* csr_src = (int*)alloc((size_t)E * 4);
    float* csr_w = (float*)alloc((size_t)E * 4);
    float* Wcat1 = (float*)alloc((size_t)F_IN * L1W * 4);
    float* Wcat2 = (float*)alloc((size_t)L1W * L2W * 4);
    float* Y = (float*)alloc((size_t)n * L1W * 4);
    float* T = (float*)alloc((size_t)n * H1 * 4);
    float* U = (float*)alloc((size_t)n * L2W * 4);
    float* T2a = (float*)alloc((size_t)n * C_OUT * 4);
    float* T2b = (float*)alloc((size_t)n * C_OUT * 4);
    (void)ws_size;

    // 0. detect edge_index dtype (int32 vs int64) and normalize to int32
    detect_k<<<1, 256, 0, stream>>>(ei, flag);
    conv_k<<<(E + 255) / 256, 256, 0, stream>>>(ei, flag, srcN, dstN, E);

    // 1. CSR build
    hipMemsetAsync(cnt, 0, (size_t)n * 4, stream);
    hist_k<<<(E + 255) / 256, 256, 0, stream>>>(dstN, cnt, E);
    dinv_k<<<(n + 255) / 256, 256, 0, stream>>>(cnt, dinv, n);
    scan_k<<<1, 1024, 0, stream>>>(cnt, rowptr, fill, n);
    scatter_k<<<(E + 255) / 256, 256, 0, stream>>>(srcN, dstN, fill, csr_src, csr_w, dinv, E);

    // 2. pack weights
    pack1_k<<<(F_IN * L1W + 255) / 256, 256, 0, stream>>>(W1_0, W1_1, W1_2, Wcat1);
    pack2_k<<<(L1W * L2W + 255) / 256, 256, 0, stream>>>(W2_0, W2_1, W2_2, Wcat2);

    // 3. layer 1: Y = X @ Wcat1  [n x 384]
    {
        dim3 grid((n + 63) / 64, (L1W + 63) / 64);
        gemm_k<<<grid, 256, 0, stream>>>(x, Wcat1, Y, n, F_IN, L1W);
    }
    // z2 = P(P(y2)): T = P(Y[:,256:384]); Y[:,256:384] = P(T)
    prop_k<128><<<n, 128, 0, stream>>>(Y, L1W, 256, T, H1, 0, rowptr, csr_src, csr_w, dinv, n);
    prop_k<128><<<n, 128, 0, stream>>>(T, H1, 0, Y, L1W, 256, rowptr, csr_src, csr_w, dinv, n);
    // z1 = P(y1): T = P(Y[:,128:256])
    prop_k<128><<<n, 128, 0, stream>>>(Y, L1W, 128, T, H1, 0, rowptr, csr_src, csr_w, dinv, n);
    // h = relu(concat + b1), in place into Y (z1 pulled from T)
    bias_relu_k<<<(n * L1W + 255) / 256, 256, 0, stream>>>(Y, T, b1, n);

    // 4. layer 2: U = H @ Wcat2  [n x 120]
    {
        dim3 grid((n + 63) / 64, (L2W + 63) / 64);
        gemm_k<<<grid, 256, 0, stream>>>(Y, Wcat2, U, n, L1W, L2W);
    }
    // v1 = P(u1) -> T2a
    prop_k<40><<<n, 64, 0, stream>>>(U, L2W, 40, T2a, C_OUT, 0, rowptr, csr_src, csr_w, dinv, n);
    // v2 = P(P(u2)): T2b = P(u2); U[:,80:120] = P(T2b)
    prop_k<40><<<n, 64, 0, stream>>>(U, L2W, 80, T2b, C_OUT, 0, rowptr, csr_src, csr_w, dinv, n);
    prop_k<40><<<n, 64, 0, stream>>>(T2b, C_OUT, 0, U, L2W, 80, rowptr, csr_src, csr_w, dinv, n);

    // 5. log_softmax epilogue
    lsm_k<<<(n + 3) / 4, 256, 0, stream>>>(U, T2a, b2, out, n);
}

// Round 4
// 758.777 us; speedup vs baseline: 1.3826x; 1.3826x over previous
//
#include <hip/hip_runtime.h>
#include <hip/hip_bf16.h>
#include <math.h>

#define N_NODES 50000
#define F_IN 256
#define H1 128
#define C_OUT 40
#define L1W 384   // 3*H1
#define L2W 120   // 3*C_OUT
#define L2WP 128  // padded

typedef __attribute__((ext_vector_type(8))) short short8;
typedef __attribute__((ext_vector_type(4))) float f32x4;
typedef __attribute__((ext_vector_type(4))) unsigned short us4;

__device__ inline unsigned short f2bf(float f) {
    union { float f; unsigned int u; } x;
    x.f = f;
    unsigned int u = x.u;
    return (unsigned short)((u + 0x7FFF + ((u >> 16) & 1)) >> 16);
}

// ---------------- edge-index dtype detection + normalization ----------------

__global__ void detect_k(const int* __restrict__ ei, int* __restrict__ flag) {
    __shared__ int any;
    if (threadIdx.x == 0) any = 0;
    __syncthreads();
    int v = 0;
    for (int r = 0; r < 4; r++) {
        int e = threadIdx.x + r * 256;
        v |= ei[e * 2 + 1];
    }
    if (v != 0) atomicOr(&any, 1);
    __syncthreads();
    if (threadIdx.x == 0) *flag = any;  // 1 => int32 layout, 0 => int64
}

__global__ void conv_k(const int* __restrict__ ei, const int* __restrict__ flag,
                       int* __restrict__ srcN, int* __restrict__ dstN, int E) {
    int e = blockIdx.x * 256 + threadIdx.x;
    if (e >= E) return;
    if (*flag) {
        srcN[e] = ei[e];
        dstN[e] = ei[E + e];
    } else {
        const long long* e64 = (const long long*)ei;
        srcN[e] = (int)e64[e];
        dstN[e] = (int)e64[E + e];
    }
}

// ---------------- CSR build ----------------

__global__ void hist_k(const int* __restrict__ dst, int* __restrict__ cnt, int E) {
    int e = blockIdx.x * 256 + threadIdx.x;
    if (e < E) atomicAdd(&cnt[dst[e]], 1);
}

__global__ void dinv_k(const int* __restrict__ cnt, float* __restrict__ dinv, int n) {
    int i = blockIdx.x * 256 + threadIdx.x;
    if (i < n) dinv[i] = rsqrtf((float)cnt[i] + 1.0f);
}

__global__ __launch_bounds__(1024) void scan_k(const int* __restrict__ cnt,
                                               int* __restrict__ rowptr,
                                               int* __restrict__ fill, int n) {
    __shared__ int sums[1024];
    int t = threadIdx.x;
    int per = (n + 1023) / 1024;
    int start = t * per;
    int end = min(start + per, n);
    int s = 0;
    for (int i = start; i < end; i++) s += cnt[i];
    sums[t] = s;
    __syncthreads();
    for (int off = 1; off < 1024; off <<= 1) {
        int v = 0;
        if (t >= off) v = sums[t - off];
        __syncthreads();
        if (t >= off) sums[t] += v;
        __syncthreads();
    }
    int run = sums[t] - s;
    for (int i = start; i < end; i++) {
        rowptr[i] = run;
        fill[i] = run;
        run += cnt[i];
    }
    if (t == 1023) rowptr[n] = sums[1023];
}

__global__ void scatter_k(const int* __restrict__ srcI, const int* __restrict__ dstI,
                          int* __restrict__ fill, int* __restrict__ csr_src,
                          float* __restrict__ csr_w, const float* __restrict__ dinv, int E) {
    int e = blockIdx.x * 256 + threadIdx.x;
    if (e >= E) return;
    int s = srcI[e], d = dstI[e];
    int pos = atomicAdd(&fill[d], 1);
    csr_src[pos] = s;
    csr_w[pos] = dinv[s] * dinv[d];
}

// ---------------- conversions / weight packing (bf16, B-fragment layout) ----
// Bp layout: [K/32][Mp][32] bf16; lane(n=lane&15 within 16-col subtile, kq=lane>>4)
// reads 8 contiguous bf16 at Bp[kt][n][kq*8] == B[kt*32+kq*8 .. +8][n].

__global__ void cvt_bf_k(const float* __restrict__ in, unsigned short* __restrict__ out, int n4) {
    int i = blockIdx.x * 256 + threadIdx.x;
    if (i >= n4) return;
    const float4 v = *(const float4*)(in + (size_t)i * 4);
    us4 o;
    o.x = f2bf(v.x); o.y = f2bf(v.y); o.z = f2bf(v.z); o.w = f2bf(v.w);
    *(us4*)(out + (size_t)i * 4) = o;
}

__global__ void pack1b_k(const float* __restrict__ w0, const float* __restrict__ w1,
                         const float* __restrict__ w2, unsigned short* __restrict__ Bp) {
    int idx = blockIdx.x * 256 + threadIdx.x;
    if (idx >= (F_IN / 32) * L1W * 32) return;
    int kk = idx & 31;
    int nn = (idx >> 5) % L1W;
    int kt = idx / (L1W * 32);
    int k = kt * 32 + kk;
    int p = nn >> 7, c = nn & 127;
    const float* w = (p == 0) ? w0 : (p == 1) ? w1 : w2;
    Bp[idx] = f2bf(w[k * H1 + c]);
}

__global__ void pack2b_k(const float* __restrict__ w0, const float* __restrict__ w1,
                         const float* __restrict__ w2, unsigned short* __restrict__ Bp) {
    int idx = blockIdx.x * 256 + threadIdx.x;
    if (idx >= (L1W / 32) * L2WP * 32) return;
    int kk = idx & 31;
    int nn = (idx >> 5) & (L2WP - 1);
    int kt = idx >> 12;  // 128*32 = 4096
    int k = kt * 32 + kk;
    unsigned short v = 0;
    if (nn < L2W) {
        int p = nn / 40, c = nn % 40;
        const float* w = (p == 0) ? w0 : (p == 1) ? w1 : w2;
        v = f2bf(w[k * C_OUT + c]);
    }
    Bp[idx] = v;
}

// ---------------- bf16 MFMA GEMM: C[NxM] fp32 = A[NxK] bf16 @ Bp ------------
// block = 4 waves; wave computes 16 rows x 64 cols; grid (ceil(N/64), Mp/64).

__global__ __launch_bounds__(256) void mgemm_k(const unsigned short* __restrict__ A,
                                               const unsigned short* __restrict__ Bp,
                                               float* __restrict__ C,
                                               int N, int K, int M, int Mp) {
    int wave = threadIdx.x >> 6, lane = threadIdx.x & 63;
    int m = lane & 15, kq = lane >> 4;
    int row0 = blockIdx.x * 64 + wave * 16;
    int col0 = blockIdx.y * 64;
    int arow = row0 + m;
    if (arow >= N) arow = N - 1;  // clamped duplicate read; stores guarded
    const unsigned short* Ap = A + (size_t)arow * K + kq * 8;
    size_t bbase = ((size_t)(col0 + m)) * 32 + kq * 8;
    f32x4 acc0 = {0.f, 0.f, 0.f, 0.f}, acc1 = acc0, acc2 = acc0, acc3 = acc0;
    int KT = K >> 5;
    for (int kt = 0; kt < KT; kt++) {
        short8 a = *(const short8*)(Ap + kt * 32);
        const unsigned short* Bkt = Bp + (size_t)kt * Mp * 32;
        short8 b0 = *(const short8*)(Bkt + bbase);
        short8 b1 = *(const short8*)(Bkt + bbase + 16 * 32);
        short8 b2 = *(const short8*)(Bkt + bbase + 32 * 32);
        short8 b3 = *(const short8*)(Bkt + bbase + 48 * 32);
        acc0 = __builtin_amdgcn_mfma_f32_16x16x32_bf16(a, b0, acc0, 0, 0, 0);
        acc1 = __builtin_amdgcn_mfma_f32_16x16x32_bf16(a, b1, acc1, 0, 0, 0);
        acc2 = __builtin_amdgcn_mfma_f32_16x16x32_bf16(a, b2, acc2, 0, 0, 0);
        acc3 = __builtin_amdgcn_mfma_f32_16x16x32_bf16(a, b3, acc3, 0, 0, 0);
    }
    // C/D layout: col = lane&15, row = (lane>>4)*4 + reg
    int crow = row0 + kq * 4;
    f32x4 accs[4] = {acc0, acc1, acc2, acc3};
#pragma unroll
    for (int s = 0; s < 4; s++) {
        int col = col0 + s * 16 + m;
        if (col < M) {
#pragma unroll
            for (int r = 0; r < 4; r++) {
                if (crow + r < N) C[(size_t)(crow + r) * M + col] = accs[s][r];
            }
        }
    }
}

// ---------------- propagation (SpMM by dst, CSR), self-loop fused -----------

template <int WIDTH>
__global__ void prop_k(const float* __restrict__ src, int slds, int soff,
                       float* __restrict__ dst, int dlds, int doff,
                       const int* __restrict__ rowptr, const int* __restrict__ csr_src,
                       const float* __restrict__ csr_w, const float* __restrict__ dinv,
                       int n) {
    int i = blockIdx.x;
    if (i >= n) return;
    int j = threadIdx.x;
    int beg = rowptr[i], end = rowptr[i + 1];
    float di = dinv[i];
    float acc = 0.f;
    if (j < WIDTH) acc = di * di * src[(size_t)i * slds + soff + j];
    int k = beg;
    for (; k + 1 < end; k += 2) {
        int s0 = csr_src[k], s1 = csr_src[k + 1];
        float w0 = csr_w[k], w1 = csr_w[k + 1];
        if (j < WIDTH) {
            float a = src[(size_t)s0 * slds + soff + j];
            float b = src[(size_t)s1 * slds + soff + j];
            acc = fmaf(w0, a, acc);
            acc = fmaf(w1, b, acc);
        }
    }
    if (k < end) {
        int s0 = csr_src[k];
        float w0 = csr_w[k];
        if (j < WIDTH) acc = fmaf(w0, src[(size_t)s0 * slds + soff + j], acc);
    }
    if (j < WIDTH) dst[(size_t)i * dlds + doff + j] = acc;
}

// ---------------- bias + relu -> bf16 H  ------------------------------------
// cols [0,128): Y  [128,256): T  [256,384): Y   out: Hb bf16 [n x 384]

__global__ void bias_relu_bf_k(const float* __restrict__ Y, const float* __restrict__ T,
                               const float* __restrict__ b1, unsigned short* __restrict__ Hb,
                               int n) {
    int idx = blockIdx.x * 256 + threadIdx.x;
    if (idx >= n * (L1W / 4)) return;
    int i = idx / (L1W / 4);
    int q = (idx % (L1W / 4)) * 4;
    float4 v;
    if (q >= 128 && q < 256) v = *(const float4*)(T + (size_t)i * H1 + (q - 128));
    else v = *(const float4*)(Y + (size_t)i * L1W + q);
    const float4 b = *(const float4*)(b1 + q);
    us4 o;
    o.x = f2bf(fmaxf(v.x + b.x, 0.f));
    o.y = f2bf(fmaxf(v.y + b.y, 0.f));
    o.z = f2bf(fmaxf(v.z + b.z, 0.f));
    o.w = f2bf(fmaxf(v.w + b.w, 0.f));
    *(us4*)(Hb + (size_t)i * L1W + q) = o;
}

// ---------------- log_softmax epilogue --------------------------------------
// col j: j<40 -> U[i,j]; 40<=j<80 -> T2a[i,j-40]; 80<=j<120 -> U[i,j]; + b2[j]

__global__ __launch_bounds__(256) void lsm_k(const float* __restrict__ U,
                                             const float* __restrict__ T2a,
                                             const float* __restrict__ b2,
                                             float* __restrict__ out, int n) {
    int wave = threadIdx.x >> 6;
    int lane = threadIdx.x & 63;
    int i = blockIdx.x * 4 + wave;
    if (i >= n) return;
    float v0, v1;
    {
        int j = lane;  // 0..63
        float v = (j >= 40) ? T2a[i * 40 + (j - 40)] : U[i * 120 + j];
        v0 = v + b2[j];
    }
    if (lane + 64 < 120) {
        int j = lane + 64;  // 64..119
        float v = (j < 80) ? T2a[i * 40 + (j - 40)] : U[i * 120 + j];
        v1 = v + b2[j];
    } else {
        v1 = -INFINITY;
    }
    float m = fmaxf(v0, v1);
    for (int off = 32; off; off >>= 1) m = fmaxf(m, __shfl_xor(m, off, 64));
    float s = expf(v0 - m) + ((lane + 64 < 120) ? expf(v1 - m) : 0.f);
    for (int off = 32; off; off >>= 1) s += __shfl_xor(s, off, 64);
    float ls = logf(s) + m;
    out[i * 120 + lane] = v0 - ls;
    if (lane + 64 < 120) out[i * 120 + lane + 64] = v1 - ls;
}

// ---------------- launch ----------------

static inline size_t align256(size_t x) { return (x + 255) & ~(size_t)255; }

extern "C" void kernel_launch(void* const* d_in, const int* in_sizes, int n_in,
                              void* d_out, int out_size, void* d_ws, size_t ws_size,
                              hipStream_t stream) {
    const float* x = (const float*)d_in[0];
    const int* ei = (const int*)d_in[1];
    const float* W1_0 = (const float*)d_in[2];
    const float* W1_1 = (const float*)d_in[3];
    const float* W1_2 = (const float*)d_in[4];
    const float* b1 = (const float*)d_in[5];
    const float* W2_0 = (const float*)d_in[6];
    const float* W2_1 = (const float*)d_in[7];
    const float* W2_2 = (const float*)d_in[8];
    const float* b2 = (const float*)d_in[9];
    float* out = (float*)d_out;

    const int n = N_NODES;
    const int E = in_sizes[1] / 2;

    char* p = (char*)d_ws;
    size_t off = 0;
    auto alloc = [&](size_t bytes) {
        void* r = p + off;
        off = align256(off + bytes);
        return r;
    };
    int* flag = (int*)alloc(4);
    int* srcN = (int*)alloc((size_t)E * 4);
    int* dstN = (int*)alloc((size_t)E * 4);
    int* cnt = (int*)alloc((size_t)n * 4);
    int* rowptr = (int*)alloc((size_t)(n + 1) * 4);
    int* fill = (int*)alloc((size_t)n * 4);
    float* dinv = (float*)alloc((size_t)n * 4);
    int* csr_src = (int*)alloc((size_t)E * 4);
    float* csr_w = (float*)alloc((size_t)E * 4);
    unsigned short* Bp1 = (unsigned short*)alloc((size_t)(F_IN / 32) * L1W * 32 * 2);
    unsigned short* Bp2 = (unsigned short*)alloc((size_t)(L1W / 32) * L2WP * 32 * 2);
    float* Y = (float*)alloc((size_t)n * L1W * 4);   // U aliases Y (Y dead by gemm2)
    float* T = (float*)alloc((size_t)n * H1 * 4);    // T2a/T2b alias T (T dead by then)
    unsigned short* Xb = (unsigned short*)alloc((size_t)n * L1W * 2);  // Hb aliases Xb
    float* U = Y;
    float* T2a = T;
    float* T2b = T + (size_t)n * C_OUT;
    unsigned short* Hb = Xb;
    (void)ws_size;

    // 0. edge dtype normalize
    detect_k<<<1, 256, 0, stream>>>(ei, flag);
    conv_k<<<(E + 255) / 256, 256, 0, stream>>>(ei, flag, srcN, dstN, E);

    // 1. CSR build
    hipMemsetAsync(cnt, 0, (size_t)n * 4, stream);
    hist_k<<<(E + 255) / 256, 256, 0, stream>>>(dstN, cnt, E);
    dinv_k<<<(n + 255) / 256, 256, 0, stream>>>(cnt, dinv, n);
    scan_k<<<1, 1024, 0, stream>>>(cnt, rowptr, fill, n);
    scatter_k<<<(E + 255) / 256, 256, 0, stream>>>(srcN, dstN, fill, csr_src, csr_w, dinv, E);

    // 2. bf16 conversions + weight packing
    cvt_bf_k<<<((n * F_IN / 4) + 255) / 256, 256, 0, stream>>>(x, Xb, n * F_IN / 4);
    pack1b_k<<<((F_IN / 32) * L1W * 32 + 255) / 256, 256, 0, stream>>>(W1_0, W1_1, W1_2, Bp1);
    pack2b_k<<<((L1W / 32) * L2WP * 32 + 255) / 256, 256, 0, stream>>>(W2_0, W2_1, W2_2, Bp2);

    // 3. layer 1: Y = Xb @ Bp1  [n x 384]
    {
        dim3 grid((n + 63) / 64, L1W / 64);
        mgemm_k<<<grid, 256, 0, stream>>>(Xb, Bp1, Y, n, F_IN, L1W, L1W);
    }
    // z2 = P(P(y2)); z1 = P(y1)
    prop_k<128><<<n, 128, 0, stream>>>(Y, L1W, 256, T, H1, 0, rowptr, csr_src, csr_w, dinv, n);
    prop_k<128><<<n, 128, 0, stream>>>(T, H1, 0, Y, L1W, 256, rowptr, csr_src, csr_w, dinv, n);
    prop_k<128><<<n, 128, 0, stream>>>(Y, L1W, 128, T, H1, 0, rowptr, csr_src, csr_w, dinv, n);
    // h = relu(concat + b1) -> bf16 Hb (overwrites Xb, which is dead)
    bias_relu_bf_k<<<((n * L1W / 4) + 255) / 256, 256, 0, stream>>>(Y, T, b1, Hb, n);

    // 4. layer 2: U = Hb @ Bp2  [n x 120]  (U aliases Y)
    {
        dim3 grid((n + 63) / 64, L2WP / 64);
        mgemm_k<<<grid, 256, 0, stream>>>(Hb, Bp2, U, n, L1W, L2W, L2WP);
    }
    // v1 = P(u1) -> T2a ; v2 = P(P(u2))
    prop_k<40><<<n, 64, 0, stream>>>(U, L2W, 40, T2a, C_OUT, 0, rowptr, csr_src, csr_w, dinv, n);
    prop_k<40><<<n, 64, 0, stream>>>(U, L2W, 80, T2b, C_OUT, 0, rowptr, csr_src, csr_w, dinv, n);
    prop_k<40><<<n, 64, 0, stream>>>(T2b, C_OUT, 0, U, L2W, 80, rowptr, csr_src, csr_w, dinv, n);

    // 5. log_softmax epilogue
    lsm_k<<<(n + 3) / 4, 256, 0, stream>>>(U, T2a, b2, out, n);
}

// Round 5
// 682.188 us; speedup vs baseline: 1.5379x; 1.1123x over previous
//
#include <hip/hip_runtime.h>
#include <hip/hip_bf16.h>
#include <math.h>

#define N_NODES 50000
#define F_IN 256
#define H1 128
#define C_OUT 40
#define L1W 384   // 3*H1
#define L2W 120   // 3*C_OUT
#define L2WP 128  // padded

typedef __attribute__((ext_vector_type(8))) short short8;
typedef __attribute__((ext_vector_type(4))) float f32x4;
typedef __attribute__((ext_vector_type(4))) unsigned short us4;

__device__ inline unsigned short f2bf(float f) {
    union { float f; unsigned int u; } x;
    x.f = f;
    unsigned int u = x.u;
    return (unsigned short)((u + 0x7FFF + ((u >> 16) & 1)) >> 16);
}

// ---------------- edge-index dtype detection + normalization ----------------

__global__ void detect_k(const int* __restrict__ ei, int* __restrict__ flag) {
    __shared__ int any;
    if (threadIdx.x == 0) any = 0;
    __syncthreads();
    int v = 0;
    for (int r = 0; r < 4; r++) {
        int e = threadIdx.x + r * 256;
        v |= ei[e * 2 + 1];
    }
    if (v != 0) atomicOr(&any, 1);
    __syncthreads();
    if (threadIdx.x == 0) *flag = any;  // 1 => int32 layout, 0 => int64
}

__global__ void conv_k(const int* __restrict__ ei, const int* __restrict__ flag,
                       int* __restrict__ srcN, int* __restrict__ dstN, int E) {
    int e = blockIdx.x * 256 + threadIdx.x;
    if (e >= E) return;
    if (*flag) {
        srcN[e] = ei[e];
        dstN[e] = ei[E + e];
    } else {
        const long long* e64 = (const long long*)ei;
        srcN[e] = (int)e64[e];
        dstN[e] = (int)e64[E + e];
    }
}

// ---------------- CSR build ----------------

__global__ void hist_k(const int* __restrict__ dst, int* __restrict__ cnt, int E) {
    int e = blockIdx.x * 256 + threadIdx.x;
    if (e < E) atomicAdd(&cnt[dst[e]], 1);
}

__global__ void dinv_k(const int* __restrict__ cnt, float* __restrict__ dinv, int n) {
    int i = blockIdx.x * 256 + threadIdx.x;
    if (i < n) dinv[i] = rsqrtf((float)cnt[i] + 1.0f);
}

// ---- three-level exclusive scan over cnt[0..n) -> rowptr[0..n], fill[0..n)

__global__ __launch_bounds__(256) void scan1_k(const int* __restrict__ cnt,
                                               int* __restrict__ bsum, int n) {
    int t = threadIdx.x;
    int i = blockIdx.x * 256 + t;
    int v = (i < n) ? cnt[i] : 0;
    for (int off = 32; off; off >>= 1) v += __shfl_down(v, off, 64);
    __shared__ int ws[4];
    if ((t & 63) == 0) ws[t >> 6] = v;
    __syncthreads();
    if (t == 0) bsum[blockIdx.x] = ws[0] + ws[1] + ws[2] + ws[3];
}

__global__ __launch_bounds__(256) void scan2_k(int* __restrict__ bsum,
                                               int* __restrict__ btot, int nb) {
    __shared__ int s[256];
    int t = threadIdx.x;
    int v = (t < nb) ? bsum[t] : 0;
    s[t] = v;
    __syncthreads();
    for (int off = 1; off < 256; off <<= 1) {
        int u = (t >= off) ? s[t - off] : 0;
        __syncthreads();
        s[t] += u;
        __syncthreads();
    }
    if (t < nb) bsum[t] = s[t] - v;  // exclusive
    if (t == nb - 1) *btot = s[t];   // rowptr[n]
}

__global__ __launch_bounds__(256) void scan3_k(const int* __restrict__ cnt,
                                               const int* __restrict__ bsum,
                                               int* __restrict__ rowptr,
                                               int* __restrict__ fill, int n) {
    __shared__ int s[256];
    int t = threadIdx.x;
    int i = blockIdx.x * 256 + t;
    int v = (i < n) ? cnt[i] : 0;
    s[t] = v;
    __syncthreads();
    for (int off = 1; off < 256; off <<= 1) {
        int u = (t >= off) ? s[t - off] : 0;
        __syncthreads();
        s[t] += u;
        __syncthreads();
    }
    if (i < n) {
        int excl = s[t] - v + bsum[blockIdx.x];
        rowptr[i] = excl;
        fill[i] = excl;
    }
}

__global__ void scatter_k(const int* __restrict__ srcI, const int* __restrict__ dstI,
                          int* __restrict__ fill, int* __restrict__ csr_src,
                          float* __restrict__ csr_w, const float* __restrict__ dinv, int E) {
    int e = blockIdx.x * 256 + threadIdx.x;
    if (e >= E) return;
    int s = srcI[e], d = dstI[e];
    int pos = atomicAdd(&fill[d], 1);
    csr_src[pos] = s;
    csr_w[pos] = dinv[s] * dinv[d];
}

// ---------------- conversions / weight packing (bf16, B-fragment layout) ----

__global__ void cvt_bf_k(const float* __restrict__ in, unsigned short* __restrict__ out, int n4) {
    int i = blockIdx.x * 256 + threadIdx.x;
    if (i >= n4) return;
    const float4 v = *(const float4*)(in + (size_t)i * 4);
    us4 o;
    o.x = f2bf(v.x); o.y = f2bf(v.y); o.z = f2bf(v.z); o.w = f2bf(v.w);
    *(us4*)(out + (size_t)i * 4) = o;
}

__global__ void pack1b_k(const float* __restrict__ w0, const float* __restrict__ w1,
                         const float* __restrict__ w2, unsigned short* __restrict__ Bp) {
    int idx = blockIdx.x * 256 + threadIdx.x;
    if (idx >= (F_IN / 32) * L1W * 32) return;
    int kk = idx & 31;
    int nn = (idx >> 5) % L1W;
    int kt = idx / (L1W * 32);
    int k = kt * 32 + kk;
    int p = nn >> 7, c = nn & 127;
    const float* w = (p == 0) ? w0 : (p == 1) ? w1 : w2;
    Bp[idx] = f2bf(w[k * H1 + c]);
}

__global__ void pack2b_k(const float* __restrict__ w0, const float* __restrict__ w1,
                         const float* __restrict__ w2, unsigned short* __restrict__ Bp) {
    int idx = blockIdx.x * 256 + threadIdx.x;
    if (idx >= (L1W / 32) * L2WP * 32) return;
    int kk = idx & 31;
    int nn = (idx >> 5) & (L2WP - 1);
    int kt = idx >> 12;  // 128*32 = 4096
    int k = kt * 32 + kk;
    unsigned short v = 0;
    if (nn < L2W) {
        int p = nn / 40, c = nn % 40;
        const float* w = (p == 0) ? w0 : (p == 1) ? w1 : w2;
        v = f2bf(w[k * C_OUT + c]);
    }
    Bp[idx] = v;
}

// ---------------- bf16 MFMA GEMM: C[NxM] fp32 = A[NxK] bf16 @ Bp ------------

__global__ __launch_bounds__(256) void mgemm_k(const unsigned short* __restrict__ A,
                                               const unsigned short* __restrict__ Bp,
                                               float* __restrict__ C,
                                               int N, int K, int M, int Mp) {
    int wave = threadIdx.x >> 6, lane = threadIdx.x & 63;
    int m = lane & 15, kq = lane >> 4;
    int row0 = blockIdx.x * 64 + wave * 16;
    int col0 = blockIdx.y * 64;
    int arow = row0 + m;
    if (arow >= N) arow = N - 1;  // clamped duplicate read; stores guarded
    const unsigned short* Ap = A + (size_t)arow * K + kq * 8;
    size_t bbase = ((size_t)(col0 + m)) * 32 + kq * 8;
    f32x4 acc0 = {0.f, 0.f, 0.f, 0.f}, acc1 = acc0, acc2 = acc0, acc3 = acc0;
    int KT = K >> 5;
    for (int kt = 0; kt < KT; kt++) {
        short8 a = *(const short8*)(Ap + kt * 32);
        const unsigned short* Bkt = Bp + (size_t)kt * Mp * 32;
        short8 b0 = *(const short8*)(Bkt + bbase);
        short8 b1 = *(const short8*)(Bkt + bbase + 16 * 32);
        short8 b2 = *(const short8*)(Bkt + bbase + 32 * 32);
        short8 b3 = *(const short8*)(Bkt + bbase + 48 * 32);
        acc0 = __builtin_amdgcn_mfma_f32_16x16x32_bf16(a, b0, acc0, 0, 0, 0);
        acc1 = __builtin_amdgcn_mfma_f32_16x16x32_bf16(a, b1, acc1, 0, 0, 0);
        acc2 = __builtin_amdgcn_mfma_f32_16x16x32_bf16(a, b2, acc2, 0, 0, 0);
        acc3 = __builtin_amdgcn_mfma_f32_16x16x32_bf16(a, b3, acc3, 0, 0, 0);
    }
    int crow = row0 + kq * 4;
    f32x4 accs[4] = {acc0, acc1, acc2, acc3};
#pragma unroll
    for (int s = 0; s < 4; s++) {
        int col = col0 + s * 16 + m;
        if (col < M) {
#pragma unroll
            for (int r = 0; r < 4; r++) {
                if (crow + r < N) C[(size_t)(crow + r) * M + col] = accs[s][r];
            }
        }
    }
}

// ---------------- propagation width 128: wave-per-node, float2/lane ---------

__global__ __launch_bounds__(256) void prop128_k(const float* __restrict__ src, int slds, int soff,
                                                 float* __restrict__ dst, int dlds, int doff,
                                                 const int* __restrict__ rowptr,
                                                 const int* __restrict__ csr_src,
                                                 const float* __restrict__ csr_w,
                                                 const float* __restrict__ dinv, int n) {
    int wave = threadIdx.x >> 6, lane = threadIdx.x & 63;
    int i = blockIdx.x * 4 + wave;
    if (i >= n) return;
    int beg = rowptr[i], end = rowptr[i + 1];
    float di = dinv[i];
    const float* sbase = src + soff + (size_t)lane * 2;
    float2 self = *(const float2*)(sbase + (size_t)i * slds);
    float accx = di * di * self.x, accy = di * di * self.y;
    int k = beg;
    for (; k + 3 < end; k += 4) {
        int i0 = csr_src[k], i1 = csr_src[k + 1], i2 = csr_src[k + 2], i3 = csr_src[k + 3];
        float w0 = csr_w[k], w1 = csr_w[k + 1], w2 = csr_w[k + 2], w3 = csr_w[k + 3];
        float2 a = *(const float2*)(sbase + (size_t)i0 * slds);
        float2 b = *(const float2*)(sbase + (size_t)i1 * slds);
        float2 c = *(const float2*)(sbase + (size_t)i2 * slds);
        float2 d = *(const float2*)(sbase + (size_t)i3 * slds);
        accx = fmaf(w0, a.x, accx); accy = fmaf(w0, a.y, accy);
        accx = fmaf(w1, b.x, accx); accy = fmaf(w1, b.y, accy);
        accx = fmaf(w2, c.x, accx); accy = fmaf(w2, c.y, accy);
        accx = fmaf(w3, d.x, accx); accy = fmaf(w3, d.y, accy);
    }
    for (; k < end; k++) {
        int s0 = csr_src[k];
        float w0 = csr_w[k];
        float2 a = *(const float2*)(sbase + (size_t)s0 * slds);
        accx = fmaf(w0, a.x, accx); accy = fmaf(w0, a.y, accy);
    }
    float2 o; o.x = accx; o.y = accy;
    *(float2*)(dst + (size_t)i * dlds + doff + lane * 2) = o;
}

// ---------------- propagation width 40 (lanes 0..39), wave-per-node ---------

__global__ __launch_bounds__(256) void prop40_k(const float* __restrict__ src, int slds, int soff,
                                                float* __restrict__ dst, int dlds, int doff,
                                                const int* __restrict__ rowptr,
                                                const int* __restrict__ csr_src,
                                                const float* __restrict__ csr_w,
                                                const float* __restrict__ dinv, int n) {
    int wave = threadIdx.x >> 6, lane = threadIdx.x & 63;
    int i = blockIdx.x * 4 + wave;
    if (i >= n) return;
    int beg = rowptr[i], end = rowptr[i + 1];
    float di = dinv[i];
    const float* sbase = src + soff + lane;
    float acc = 0.f;
    if (lane < 40) acc = di * di * sbase[(size_t)i * slds];
    int k = beg;
    for (; k + 1 < end; k += 2) {
        int i0 = csr_src[k], i1 = csr_src[k + 1];
        float w0 = csr_w[k], w1 = csr_w[k + 1];
        if (lane < 40) {
            float a = sbase[(size_t)i0 * slds];
            float b = sbase[(size_t)i1 * slds];
            acc = fmaf(w0, a, acc);
            acc = fmaf(w1, b, acc);
        }
    }
    if (k < end) {
        int i0 = csr_src[k];
        float w0 = csr_w[k];
        if (lane < 40) acc = fmaf(w0, sbase[(size_t)i0 * slds], acc);
    }
    if (lane < 40) dst[(size_t)i * dlds + doff + lane] = acc;
}

// ---------------- bias + relu -> bf16 H  ------------------------------------

__global__ void bias_relu_bf_k(const float* __restrict__ Y, const float* __restrict__ T,
                               const float* __restrict__ b1, unsigned short* __restrict__ Hb,
                               int n) {
    int idx = blockIdx.x * 256 + threadIdx.x;
    if (idx >= n * (L1W / 4)) return;
    int i = idx / (L1W / 4);
    int q = (idx % (L1W / 4)) * 4;
    float4 v;
    if (q >= 128 && q < 256) v = *(const float4*)(T + (size_t)i * H1 + (q - 128));
    else v = *(const float4*)(Y + (size_t)i * L1W + q);
    const float4 b = *(const float4*)(b1 + q);
    us4 o;
    o.x = f2bf(fmaxf(v.x + b.x, 0.f));
    o.y = f2bf(fmaxf(v.y + b.y, 0.f));
    o.z = f2bf(fmaxf(v.z + b.z, 0.f));
    o.w = f2bf(fmaxf(v.w + b.w, 0.f));
    *(us4*)(Hb + (size_t)i * L1W + q) = o;
}

// ---------------- log_softmax epilogue --------------------------------------

__global__ __launch_bounds__(256) void lsm_k(const float* __restrict__ U,
                                             const float* __restrict__ T2a,
                                             const float* __restrict__ b2,
                                             float* __restrict__ out, int n) {
    int wave = threadIdx.x >> 6;
    int lane = threadIdx.x & 63;
    int i = blockIdx.x * 4 + wave;
    if (i >= n) return;
    float v0, v1;
    {
        int j = lane;  // 0..63
        float v = (j >= 40) ? T2a[i * 40 + (j - 40)] : U[i * 120 + j];
        v0 = v + b2[j];
    }
    if (lane + 64 < 120) {
        int j = lane + 64;  // 64..119
        float v = (j < 80) ? T2a[i * 40 + (j - 40)] : U[i * 120 + j];
        v1 = v + b2[j];
    } else {
        v1 = -INFINITY;
    }
    float m = fmaxf(v0, v1);
    for (int off = 32; off; off >>= 1) m = fmaxf(m, __shfl_xor(m, off, 64));
    float s = expf(v0 - m) + ((lane + 64 < 120) ? expf(v1 - m) : 0.f);
    for (int off = 32; off; off >>= 1) s += __shfl_xor(s, off, 64);
    float ls = logf(s) + m;
    out[i * 120 + lane] = v0 - ls;
    if (lane + 64 < 120) out[i * 120 + lane + 64] = v1 - ls;
}

// ---------------- launch ----------------

static inline size_t align256(size_t x) { return (x + 255) & ~(size_t)255; }

extern "C" void kernel_launch(void* const* d_in, const int* in_sizes, int n_in,
                              void* d_out, int out_size, void* d_ws, size_t ws_size,
                              hipStream_t stream) {
    const float* x = (const float*)d_in[0];
    const int* ei = (const int*)d_in[1];
    const float* W1_0 = (const float*)d_in[2];
    const float* W1_1 = (const float*)d_in[3];
    const float* W1_2 = (const float*)d_in[4];
    const float* b1 = (const float*)d_in[5];
    const float* W2_0 = (const float*)d_in[6];
    const float* W2_1 = (const float*)d_in[7];
    const float* W2_2 = (const float*)d_in[8];
    const float* b2 = (const float*)d_in[9];
    float* out = (float*)d_out;

    const int n = N_NODES;
    const int E = in_sizes[1] / 2;
    const int nb = (n + 255) / 256;

    char* p = (char*)d_ws;
    size_t off = 0;
    auto alloc = [&](size_t bytes) {
        void* r = p + off;
        off = align256(off + bytes);
        return r;
    };
    int* flag = (int*)alloc(4);
    int* srcN = (int*)alloc((size_t)E * 4);
    int* dstN = (int*)alloc((size_t)E * 4);
    int* cnt = (int*)alloc((size_t)n * 4);
    int* rowptr = (int*)alloc((size_t)(n + 1) * 4);
    int* fill = (int*)alloc((size_t)n * 4);
    int* bsum = (int*)alloc((size_t)nb * 4);
    float* dinv = (float*)alloc((size_t)n * 4);
    int* csr_src = (int*)alloc((size_t)E * 4);
    float* csr_w = (float*)alloc((size_t)E * 4);
    unsigned short* Bp1 = (unsigned short*)alloc((size_t)(F_IN / 32) * L1W * 32 * 2);
    unsigned short* Bp2 = (unsigned short*)alloc((size_t)(L1W / 32) * L2WP * 32 * 2);
    float* Y = (float*)alloc((size_t)n * L1W * 4);   // U aliases Y
    float* T = (float*)alloc((size_t)n * H1 * 4);    // T2a/T2b alias T
    unsigned short* Xb = (unsigned short*)alloc((size_t)n * L1W * 2);  // Hb aliases Xb
    float* U = Y;
    float* T2a = T;
    float* T2b = T + (size_t)n * C_OUT;
    unsigned short* Hb = Xb;
    (void)ws_size;

    // 0. edge dtype normalize
    detect_k<<<1, 256, 0, stream>>>(ei, flag);
    conv_k<<<(E + 255) / 256, 256, 0, stream>>>(ei, flag, srcN, dstN, E);

    // 1. CSR build
    hipMemsetAsync(cnt, 0, (size_t)n * 4, stream);
    hist_k<<<(E + 255) / 256, 256, 0, stream>>>(dstN, cnt, E);
    dinv_k<<<(n + 255) / 256, 256, 0, stream>>>(cnt, dinv, n);
    scan1_k<<<nb, 256, 0, stream>>>(cnt, bsum, n);
    scan2_k<<<1, 256, 0, stream>>>(bsum, rowptr + n, nb);
    scan3_k<<<nb, 256, 0, stream>>>(cnt, bsum, rowptr, fill, n);
    scatter_k<<<(E + 255) / 256, 256, 0, stream>>>(srcN, dstN, fill, csr_src, csr_w, dinv, E);

    // 2. bf16 conversions + weight packing
    cvt_bf_k<<<((n * F_IN / 4) + 255) / 256, 256, 0, stream>>>(x, Xb, n * F_IN / 4);
    pack1b_k<<<((F_IN / 32) * L1W * 32 + 255) / 256, 256, 0, stream>>>(W1_0, W1_1, W1_2, Bp1);
    pack2b_k<<<((L1W / 32) * L2WP * 32 + 255) / 256, 256, 0, stream>>>(W2_0, W2_1, W2_2, Bp2);

    // 3. layer 1: Y = Xb @ Bp1  [n x 384]
    {
        dim3 grid((n + 63) / 64, L1W / 64);
        mgemm_k<<<grid, 256, 0, stream>>>(Xb, Bp1, Y, n, F_IN, L1W, L1W);
    }
    // z2 = P(P(y2)); z1 = P(y1)
    prop128_k<<<(n + 3) / 4, 256, 0, stream>>>(Y, L1W, 256, T, H1, 0, rowptr, csr_src, csr_w, dinv, n);
    prop128_k<<<(n + 3) / 4, 256, 0, stream>>>(T, H1, 0, Y, L1W, 256, rowptr, csr_src, csr_w, dinv, n);
    prop128_k<<<(n + 3) / 4, 256, 0, stream>>>(Y, L1W, 128, T, H1, 0, rowptr, csr_src, csr_w, dinv, n);
    // h = relu(concat + b1) -> bf16 Hb
    bias_relu_bf_k<<<((n * L1W / 4) + 255) / 256, 256, 0, stream>>>(Y, T, b1, Hb, n);

    // 4. layer 2: U = Hb @ Bp2  [n x 120]
    {
        dim3 grid((n + 63) / 64, L2WP / 64);
        mgemm_k<<<grid, 256, 0, stream>>>(Hb, Bp2, U, n, L1W, L2W, L2WP);
    }
    // v1 = P(u1) -> T2a ; v2 = P(P(u2))
    prop40_k<<<(n + 3) / 4, 256, 0, stream>>>(U, L2W, 40, T2a, C_OUT, 0, rowptr, csr_src, csr_w, dinv, n);
    prop40_k<<<(n + 3) / 4, 256, 0, stream>>>(U, L2W, 80, T2b, C_OUT, 0, rowptr, csr_src, csr_w, dinv, n);
    prop40_k<<<(n + 3) / 4, 256, 0, stream>>>(T2b, C_OUT, 0, U, L2W, 80, rowptr, csr_src, csr_w, dinv, n);

    // 5. log_softmax epilogue
    lsm_k<<<(n + 3) / 4, 256, 0, stream>>>(U, T2a, b2, out, n);
}

// Round 6
// 529.514 us; speedup vs baseline: 1.9813x; 1.2883x over previous
//
#include <hip/hip_runtime.h>
#include <hip/hip_bf16.h>
#include <math.h>

#define N_NODES 50000
#define F_IN 256
#define H1 128
#define C_OUT 40
#define L1W 384   // 3*H1
#define L2W 120   // 3*C_OUT
#define L2WP 128  // padded

typedef __attribute__((ext_vector_type(8))) short short8;
typedef __attribute__((ext_vector_type(4))) float f32x4;
typedef __attribute__((ext_vector_type(4))) unsigned short us4;

__device__ inline unsigned short f2bf(float f) {
    union { float f; unsigned int u; } x;
    x.f = f;
    unsigned int u = x.u;
    return (unsigned short)((u + 0x7FFF + ((u >> 16) & 1)) >> 16);
}
__device__ inline float bf2f(unsigned short u) {
    union { unsigned int u; float f; } x;
    x.u = (unsigned int)u << 16;
    return x.f;
}

// ---------------- edge-index dtype detection + normalization ----------------

__global__ void detect_k(const int* __restrict__ ei, int* __restrict__ flag) {
    __shared__ int any;
    if (threadIdx.x == 0) any = 0;
    __syncthreads();
    int v = 0;
    for (int r = 0; r < 4; r++) {
        int e = threadIdx.x + r * 256;
        v |= ei[e * 2 + 1];
    }
    if (v != 0) atomicOr(&any, 1);
    __syncthreads();
    if (threadIdx.x == 0) *flag = any;  // 1 => int32 layout, 0 => int64
}

__global__ void conv_k(const int* __restrict__ ei, const int* __restrict__ flag,
                       int* __restrict__ srcN, int* __restrict__ dstN, int E) {
    int e = blockIdx.x * 256 + threadIdx.x;
    if (e >= E) return;
    if (*flag) {
        srcN[e] = ei[e];
        dstN[e] = ei[E + e];
    } else {
        const long long* e64 = (const long long*)ei;
        srcN[e] = (int)e64[e];
        dstN[e] = (int)e64[E + e];
    }
}

// ---------------- CSR build ----------------

__global__ void hist_k(const int* __restrict__ dst, int* __restrict__ cnt, int E) {
    int e = blockIdx.x * 256 + threadIdx.x;
    if (e < E) atomicAdd(&cnt[dst[e]], 1);
}

__global__ void dinv_k(const int* __restrict__ cnt, float* __restrict__ dinv, int n) {
    int i = blockIdx.x * 256 + threadIdx.x;
    if (i < n) dinv[i] = rsqrtf((float)cnt[i] + 1.0f);
}

// ---- three-level exclusive scan over cnt[0..n) -> rowptr[0..n], fill[0..n)

__global__ __launch_bounds__(256) void scan1_k(const int* __restrict__ cnt,
                                               int* __restrict__ bsum, int n) {
    int t = threadIdx.x;
    int i = blockIdx.x * 256 + t;
    int v = (i < n) ? cnt[i] : 0;
    for (int off = 32; off; off >>= 1) v += __shfl_down(v, off, 64);
    __shared__ int ws[4];
    if ((t & 63) == 0) ws[t >> 6] = v;
    __syncthreads();
    if (t == 0) bsum[blockIdx.x] = ws[0] + ws[1] + ws[2] + ws[3];
}

__global__ __launch_bounds__(256) void scan2_k(int* __restrict__ bsum,
                                               int* __restrict__ btot, int nb) {
    __shared__ int s[256];
    int t = threadIdx.x;
    int v = (t < nb) ? bsum[t] : 0;
    s[t] = v;
    __syncthreads();
    for (int off = 1; off < 256; off <<= 1) {
        int u = (t >= off) ? s[t - off] : 0;
        __syncthreads();
        s[t] += u;
        __syncthreads();
    }
    if (t < nb) bsum[t] = s[t] - v;  // exclusive
    if (t == nb - 1) *btot = s[t];   // rowptr[n]
}

__global__ __launch_bounds__(256) void scan3_k(const int* __restrict__ cnt,
                                               const int* __restrict__ bsum,
                                               int* __restrict__ rowptr,
                                               int* __restrict__ fill, int n) {
    __shared__ int s[256];
    int t = threadIdx.x;
    int i = blockIdx.x * 256 + t;
    int v = (i < n) ? cnt[i] : 0;
    s[t] = v;
    __syncthreads();
    for (int off = 1; off < 256; off <<= 1) {
        int u = (t >= off) ? s[t - off] : 0;
        __syncthreads();
        s[t] += u;
        __syncthreads();
    }
    if (i < n) {
        int excl = s[t] - v + bsum[blockIdx.x];
        rowptr[i] = excl;
        fill[i] = excl;
    }
}

__global__ void scatter_k(const int* __restrict__ srcI, const int* __restrict__ dstI,
                          int* __restrict__ fill, int* __restrict__ csr_src,
                          float* __restrict__ csr_w, const float* __restrict__ dinv, int E) {
    int e = blockIdx.x * 256 + threadIdx.x;
    if (e >= E) return;
    int s = srcI[e], d = dstI[e];
    int pos = atomicAdd(&fill[d], 1);
    csr_src[pos] = s;
    csr_w[pos] = dinv[s] * dinv[d];
}

// ---------------- conversions / weight packing (bf16, B-fragment layout) ----

__global__ void cvt_bf_k(const float* __restrict__ in, unsigned short* __restrict__ out, int n4) {
    int i = blockIdx.x * 256 + threadIdx.x;
    if (i >= n4) return;
    const float4 v = *(const float4*)(in + (size_t)i * 4);
    us4 o;
    o.x = f2bf(v.x); o.y = f2bf(v.y); o.z = f2bf(v.z); o.w = f2bf(v.w);
    *(us4*)(out + (size_t)i * 4) = o;
}

__global__ void pack1b_k(const float* __restrict__ w0, const float* __restrict__ w1,
                         const float* __restrict__ w2, unsigned short* __restrict__ Bp) {
    int idx = blockIdx.x * 256 + threadIdx.x;
    if (idx >= (F_IN / 32) * L1W * 32) return;
    int kk = idx & 31;
    int nn = (idx >> 5) % L1W;
    int kt = idx / (L1W * 32);
    int k = kt * 32 + kk;
    int p = nn >> 7, c = nn & 127;
    const float* w = (p == 0) ? w0 : (p == 1) ? w1 : w2;
    Bp[idx] = f2bf(w[k * H1 + c]);
}

__global__ void pack2b_k(const float* __restrict__ w0, const float* __restrict__ w1,
                         const float* __restrict__ w2, unsigned short* __restrict__ Bp) {
    int idx = blockIdx.x * 256 + threadIdx.x;
    if (idx >= (L1W / 32) * L2WP * 32) return;
    int kk = idx & 31;
    int nn = (idx >> 5) & (L2WP - 1);
    int kt = idx >> 12;  // 128*32 = 4096
    int k = kt * 32 + kk;
    unsigned short v = 0;
    if (nn < L2W) {
        int p = nn / 40, c = nn % 40;
        const float* w = (p == 0) ? w0 : (p == 1) ? w1 : w2;
        v = f2bf(w[k * C_OUT + c]);
    }
    Bp[idx] = v;
}

// ---------------- bf16 MFMA GEMM, bf16 C output (layer 1) -------------------
// block = 4 waves; wave computes 16 rows x 64 cols; grid (ceil(N/64), Mp/64).

__global__ __launch_bounds__(256) void mgemm_bf_k(const unsigned short* __restrict__ A,
                                                  const unsigned short* __restrict__ Bp,
                                                  unsigned short* __restrict__ C,
                                                  int N, int K, int M, int Mp) {
    int wave = threadIdx.x >> 6, lane = threadIdx.x & 63;
    int m = lane & 15, kq = lane >> 4;
    int row0 = blockIdx.x * 64 + wave * 16;
    int col0 = blockIdx.y * 64;
    int arow = row0 + m;
    if (arow >= N) arow = N - 1;
    const unsigned short* Ap = A + (size_t)arow * K + kq * 8;
    size_t bbase = ((size_t)(col0 + m)) * 32 + kq * 8;
    f32x4 acc0 = {0.f, 0.f, 0.f, 0.f}, acc1 = acc0, acc2 = acc0, acc3 = acc0;
    int KT = K >> 5;
    for (int kt = 0; kt < KT; kt++) {
        short8 a = *(const short8*)(Ap + kt * 32);
        const unsigned short* Bkt = Bp + (size_t)kt * Mp * 32;
        short8 b0 = *(const short8*)(Bkt + bbase);
        short8 b1 = *(const short8*)(Bkt + bbase + 16 * 32);
        short8 b2 = *(const short8*)(Bkt + bbase + 32 * 32);
        short8 b3 = *(const short8*)(Bkt + bbase + 48 * 32);
        acc0 = __builtin_amdgcn_mfma_f32_16x16x32_bf16(a, b0, acc0, 0, 0, 0);
        acc1 = __builtin_amdgcn_mfma_f32_16x16x32_bf16(a, b1, acc1, 0, 0, 0);
        acc2 = __builtin_amdgcn_mfma_f32_16x16x32_bf16(a, b2, acc2, 0, 0, 0);
        acc3 = __builtin_amdgcn_mfma_f32_16x16x32_bf16(a, b3, acc3, 0, 0, 0);
    }
    int crow = row0 + kq * 4;
    f32x4 accs[4] = {acc0, acc1, acc2, acc3};
#pragma unroll
    for (int s = 0; s < 4; s++) {
        int col = col0 + s * 16 + m;
        if (col < M) {
#pragma unroll
            for (int r = 0; r < 4; r++) {
                if (crow + r < N) C[(size_t)(crow + r) * M + col] = f2bf(accs[s][r]);
            }
        }
    }
}

// ---------------- bf16 MFMA GEMM, fp32 C output (layer 2) -------------------

__global__ __launch_bounds__(256) void mgemm_k(const unsigned short* __restrict__ A,
                                               const unsigned short* __restrict__ Bp,
                                               float* __restrict__ C,
                                               int N, int K, int M, int Mp) {
    int wave = threadIdx.x >> 6, lane = threadIdx.x & 63;
    int m = lane & 15, kq = lane >> 4;
    int row0 = blockIdx.x * 64 + wave * 16;
    int col0 = blockIdx.y * 64;
    int arow = row0 + m;
    if (arow >= N) arow = N - 1;
    const unsigned short* Ap = A + (size_t)arow * K + kq * 8;
    size_t bbase = ((size_t)(col0 + m)) * 32 + kq * 8;
    f32x4 acc0 = {0.f, 0.f, 0.f, 0.f}, acc1 = acc0, acc2 = acc0, acc3 = acc0;
    int KT = K >> 5;
    for (int kt = 0; kt < KT; kt++) {
        short8 a = *(const short8*)(Ap + kt * 32);
        const unsigned short* Bkt = Bp + (size_t)kt * Mp * 32;
        short8 b0 = *(const short8*)(Bkt + bbase);
        short8 b1 = *(const short8*)(Bkt + bbase + 16 * 32);
        short8 b2 = *(const short8*)(Bkt + bbase + 32 * 32);
        short8 b3 = *(const short8*)(Bkt + bbase + 48 * 32);
        acc0 = __builtin_amdgcn_mfma_f32_16x16x32_bf16(a, b0, acc0, 0, 0, 0);
        acc1 = __builtin_amdgcn_mfma_f32_16x16x32_bf16(a, b1, acc1, 0, 0, 0);
        acc2 = __builtin_amdgcn_mfma_f32_16x16x32_bf16(a, b2, acc2, 0, 0, 0);
        acc3 = __builtin_amdgcn_mfma_f32_16x16x32_bf16(a, b3, acc3, 0, 0, 0);
    }
    int crow = row0 + kq * 4;
    f32x4 accs[4] = {acc0, acc1, acc2, acc3};
#pragma unroll
    for (int s = 0; s < 4; s++) {
        int col = col0 + s * 16 + m;
        if (col < M) {
#pragma unroll
            for (int r = 0; r < 4; r++) {
                if (crow + r < N) C[(size_t)(crow + r) * M + col] = accs[s][r];
            }
        }
    }
}

// ---------------- fused width-256 bf16 prop: z1|t = P(Yb[:,128:384]) --------
// Tz[i, 0:128] = P(y1), Tz[i, 128:256] = P(y2). Wave-per-node, us4 (4 bf16)/lane.

__global__ __launch_bounds__(256) void prop256b_k(const unsigned short* __restrict__ Yb,
                                                  unsigned short* __restrict__ Tz,
                                                  const int* __restrict__ rowptr,
                                                  const int* __restrict__ csr_src,
                                                  const float* __restrict__ csr_w,
                                                  const float* __restrict__ dinv, int n) {
    int wave = threadIdx.x >> 6, lane = threadIdx.x & 63;
    int i = blockIdx.x * 4 + wave;
    if (i >= n) return;
    int beg = rowptr[i], end = rowptr[i + 1];
    float di = dinv[i];
    const unsigned short* sbase = Yb + 128 + (size_t)lane * 4;
    us4 sv = *(const us4*)(sbase + (size_t)i * L1W);
    float w = di * di;
    float a0 = w * bf2f(sv.x), a1 = w * bf2f(sv.y), a2 = w * bf2f(sv.z), a3 = w * bf2f(sv.w);
    int k = beg;
    for (; k + 3 < end; k += 4) {
        int i0 = csr_src[k], i1 = csr_src[k + 1], i2 = csr_src[k + 2], i3 = csr_src[k + 3];
        float w0 = csr_w[k], w1 = csr_w[k + 1], w2 = csr_w[k + 2], w3 = csr_w[k + 3];
        us4 v0 = *(const us4*)(sbase + (size_t)i0 * L1W);
        us4 v1 = *(const us4*)(sbase + (size_t)i1 * L1W);
        us4 v2 = *(const us4*)(sbase + (size_t)i2 * L1W);
        us4 v3 = *(const us4*)(sbase + (size_t)i3 * L1W);
        a0 = fmaf(w0, bf2f(v0.x), a0); a1 = fmaf(w0, bf2f(v0.y), a1);
        a2 = fmaf(w0, bf2f(v0.z), a2); a3 = fmaf(w0, bf2f(v0.w), a3);
        a0 = fmaf(w1, bf2f(v1.x), a0); a1 = fmaf(w1, bf2f(v1.y), a1);
        a2 = fmaf(w1, bf2f(v1.z), a2); a3 = fmaf(w1, bf2f(v1.w), a3);
        a0 = fmaf(w2, bf2f(v2.x), a0); a1 = fmaf(w2, bf2f(v2.y), a1);
        a2 = fmaf(w2, bf2f(v2.z), a2); a3 = fmaf(w2, bf2f(v2.w), a3);
        a0 = fmaf(w3, bf2f(v3.x), a0); a1 = fmaf(w3, bf2f(v3.y), a1);
        a2 = fmaf(w3, bf2f(v3.z), a2); a3 = fmaf(w3, bf2f(v3.w), a3);
    }
    for (; k < end; k++) {
        int i0 = csr_src[k];
        float w0 = csr_w[k];
        us4 v0 = *(const us4*)(sbase + (size_t)i0 * L1W);
        a0 = fmaf(w0, bf2f(v0.x), a0); a1 = fmaf(w0, bf2f(v0.y), a1);
        a2 = fmaf(w0, bf2f(v0.z), a2); a3 = fmaf(w0, bf2f(v0.w), a3);
    }
    us4 o;
    o.x = f2bf(a0); o.y = f2bf(a1); o.z = f2bf(a2); o.w = f2bf(a3);
    *(us4*)(Tz + (size_t)i * 256 + lane * 4) = o;
}

// ---------------- width-128 bf16 prop: Yb[:,256:384] = P(Tz[:,128:256]) -----

__global__ __launch_bounds__(256) void prop128b_k(const unsigned short* __restrict__ Tz,
                                                  unsigned short* __restrict__ Yb,
                                                  const int* __restrict__ rowptr,
                                                  const int* __restrict__ csr_src,
                                                  const float* __restrict__ csr_w,
                                                  const float* __restrict__ dinv, int n) {
    int wave = threadIdx.x >> 6, lane = threadIdx.x & 63;
    int i = blockIdx.x * 4 + wave;
    if (i >= n) return;
    int beg = rowptr[i], end = rowptr[i + 1];
    float di = dinv[i];
    const unsigned int* sbase = (const unsigned int*)(Tz + 128) + lane;
    unsigned int sv = sbase[(size_t)i * 128];  // 256 ushorts = 128 uints per row
    float w = di * di;
    float a0 = w * bf2f((unsigned short)sv), a1 = w * bf2f((unsigned short)(sv >> 16));
    int k = beg;
    for (; k + 3 < end; k += 4) {
        int i0 = csr_src[k], i1 = csr_src[k + 1], i2 = csr_src[k + 2], i3 = csr_src[k + 3];
        float w0 = csr_w[k], w1 = csr_w[k + 1], w2 = csr_w[k + 2], w3 = csr_w[k + 3];
        unsigned int v0 = sbase[(size_t)i0 * 128];
        unsigned int v1 = sbase[(size_t)i1 * 128];
        unsigned int v2 = sbase[(size_t)i2 * 128];
        unsigned int v3 = sbase[(size_t)i3 * 128];
        a0 = fmaf(w0, bf2f((unsigned short)v0), a0); a1 = fmaf(w0, bf2f((unsigned short)(v0 >> 16)), a1);
        a0 = fmaf(w1, bf2f((unsigned short)v1), a0); a1 = fmaf(w1, bf2f((unsigned short)(v1 >> 16)), a1);
        a0 = fmaf(w2, bf2f((unsigned short)v2), a0); a1 = fmaf(w2, bf2f((unsigned short)(v2 >> 16)), a1);
        a0 = fmaf(w3, bf2f((unsigned short)v3), a0); a1 = fmaf(w3, bf2f((unsigned short)(v3 >> 16)), a1);
    }
    for (; k < end; k++) {
        int i0 = csr_src[k];
        float w0 = csr_w[k];
        unsigned int v0 = sbase[(size_t)i0 * 128];
        a0 = fmaf(w0, bf2f((unsigned short)v0), a0); a1 = fmaf(w0, bf2f((unsigned short)(v0 >> 16)), a1);
    }
    unsigned int o = (unsigned int)f2bf(a0) | ((unsigned int)f2bf(a1) << 16);
    *((unsigned int*)(Yb + (size_t)i * L1W + 256) + lane) = o;
}

// ---------------- fused width-80 fp32 prop (layer 2): T2a|T2b = P(U[:,40:120])

__global__ __launch_bounds__(256) void prop80_k(const float* __restrict__ U,
                                                float* __restrict__ T2a, float* __restrict__ T2b,
                                                const int* __restrict__ rowptr,
                                                const int* __restrict__ csr_src,
                                                const float* __restrict__ csr_w,
                                                const float* __restrict__ dinv, int n) {
    int wave = threadIdx.x >> 6, lane = threadIdx.x & 63;
    int i = blockIdx.x * 4 + wave;
    if (i >= n) return;
    int beg = rowptr[i], end = rowptr[i + 1];
    float di = dinv[i];
    bool act = lane < 40;
    const float* sbase = U + 40 + (size_t)lane * 2;
    float accx = 0.f, accy = 0.f;
    if (act) {
        float2 sv = *(const float2*)(sbase + (size_t)i * L2W);
        accx = di * di * sv.x; accy = di * di * sv.y;
    }
    int k = beg;
    for (; k + 1 < end; k += 2) {
        int i0 = csr_src[k], i1 = csr_src[k + 1];
        float w0 = csr_w[k], w1 = csr_w[k + 1];
        if (act) {
            float2 a = *(const float2*)(sbase + (size_t)i0 * L2W);
            float2 b = *(const float2*)(sbase + (size_t)i1 * L2W);
            accx = fmaf(w0, a.x, accx); accy = fmaf(w0, a.y, accy);
            accx = fmaf(w1, b.x, accx); accy = fmaf(w1, b.y, accy);
        }
    }
    if (k < end) {
        int i0 = csr_src[k];
        float w0 = csr_w[k];
        if (act) {
            float2 a = *(const float2*)(sbase + (size_t)i0 * L2W);
            accx = fmaf(w0, a.x, accx); accy = fmaf(w0, a.y, accy);
        }
    }
    if (act) {
        int c = lane * 2;  // 0..78 -> logical col 40+c
        float2 o; o.x = accx; o.y = accy;
        if (c < 40) *(float2*)(T2a + (size_t)i * 40 + c) = o;
        else *(float2*)(T2b + (size_t)i * 40 + (c - 40)) = o;
    }
}

// ---------------- width-40 fp32 prop (second hop): U[:,80:120] = P(T2b) -----

__global__ __launch_bounds__(256) void prop40_k(const float* __restrict__ src, int slds, int soff,
                                                float* __restrict__ dst, int dlds, int doff,
                                                const int* __restrict__ rowptr,
                                                const int* __restrict__ csr_src,
                                                const float* __restrict__ csr_w,
                                                const float* __restrict__ dinv, int n) {
    int wave = threadIdx.x >> 6, lane = threadIdx.x & 63;
    int i = blockIdx.x * 4 + wave;
    if (i >= n) return;
    int beg = rowptr[i], end = rowptr[i + 1];
    float di = dinv[i];
    const float* sbase = src + soff + lane;
    float acc = 0.f;
    if (lane < 40) acc = di * di * sbase[(size_t)i * slds];
    int k = beg;
    for (; k + 1 < end; k += 2) {
        int i0 = csr_src[k], i1 = csr_src[k + 1];
        float w0 = csr_w[k], w1 = csr_w[k + 1];
        if (lane < 40) {
            float a = sbase[(size_t)i0 * slds];
            float b = sbase[(size_t)i1 * slds];
            acc = fmaf(w0, a, acc);
            acc = fmaf(w1, b, acc);
        }
    }
    if (k < end) {
        int i0 = csr_src[k];
        float w0 = csr_w[k];
        if (lane < 40) acc = fmaf(w0, sbase[(size_t)i0 * slds], acc);
    }
    if (lane < 40) dst[(size_t)i * dlds + doff + lane] = acc;
}

// ---------------- bias + relu -> bf16 H -------------------------------------
// h cols [0,128): Yb  [128,256): Tz[0:128]  [256,384): Yb

__global__ void bias_relu_bf_k(const unsigned short* __restrict__ Yb,
                               const unsigned short* __restrict__ Tz,
                               const float* __restrict__ b1, unsigned short* __restrict__ Hb,
                               int n) {
    int idx = blockIdx.x * 256 + threadIdx.x;
    if (idx >= n * (L1W / 4)) return;
    int i = idx / (L1W / 4);
    int q = (idx % (L1W / 4)) * 4;
    us4 v;
    if (q >= 128 && q < 256) v = *(const us4*)(Tz + (size_t)i * 256 + (q - 128));
    else v = *(const us4*)(Yb + (size_t)i * L1W + q);
    const float4 b = *(const float4*)(b1 + q);
    us4 o;
    o.x = f2bf(fmaxf(bf2f(v.x) + b.x, 0.f));
    o.y = f2bf(fmaxf(bf2f(v.y) + b.y, 0.f));
    o.z = f2bf(fmaxf(bf2f(v.z) + b.z, 0.f));
    o.w = f2bf(fmaxf(bf2f(v.w) + b.w, 0.f));
    *(us4*)(Hb + (size_t)i * L1W + q) = o;
}

// ---------------- log_softmax epilogue --------------------------------------

__global__ __launch_bounds__(256) void lsm_k(const float* __restrict__ U,
                                             const float* __restrict__ T2a,
                                             const float* __restrict__ b2,
                                             float* __restrict__ out, int n) {
    int wave = threadIdx.x >> 6;
    int lane = threadIdx.x & 63;
    int i = blockIdx.x * 4 + wave;
    if (i >= n) return;
    float v0, v1;
    {
        int j = lane;  // 0..63
        float v = (j >= 40) ? T2a[i * 40 + (j - 40)] : U[i * 120 + j];
        v0 = v + b2[j];
    }
    if (lane + 64 < 120) {
        int j = lane + 64;  // 64..119
        float v = (j < 80) ? T2a[i * 40 + (j - 40)] : U[i * 120 + j];
        v1 = v + b2[j];
    } else {
        v1 = -INFINITY;
    }
    float m = fmaxf(v0, v1);
    for (int off = 32; off; off >>= 1) m = fmaxf(m, __shfl_xor(m, off, 64));
    float s = expf(v0 - m) + ((lane + 64 < 120) ? expf(v1 - m) : 0.f);
    for (int off = 32; off; off >>= 1) s += __shfl_xor(s, off, 64);
    float ls = logf(s) + m;
    out[i * 120 + lane] = v0 - ls;
    if (lane + 64 < 120) out[i * 120 + lane + 64] = v1 - ls;
}

// ---------------- launch ----------------

static inline size_t align256(size_t x) { return (x + 255) & ~(size_t)255; }

extern "C" void kernel_launch(void* const* d_in, const int* in_sizes, int n_in,
                              void* d_out, int out_size, void* d_ws, size_t ws_size,
                              hipStream_t stream) {
    const float* x = (const float*)d_in[0];
    const int* ei = (const int*)d_in[1];
    const float* W1_0 = (const float*)d_in[2];
    const float* W1_1 = (const float*)d_in[3];
    const float* W1_2 = (const float*)d_in[4];
    const float* b1 = (const float*)d_in[5];
    const float* W2_0 = (const float*)d_in[6];
    const float* W2_1 = (const float*)d_in[7];
    const float* W2_2 = (const float*)d_in[8];
    const float* b2 = (const float*)d_in[9];
    float* out = (float*)d_out;

    const int n = N_NODES;
    const int E = in_sizes[1] / 2;
    const int nb = (n + 255) / 256;

    char* p = (char*)d_ws;
    size_t off = 0;
    auto alloc = [&](size_t bytes) {
        void* r = p + off;
        off = align256(off + bytes);
        return r;
    };
    int* flag = (int*)alloc(4);
    int* srcN = (int*)alloc((size_t)E * 4);
    int* dstN = (int*)alloc((size_t)E * 4);
    int* cnt = (int*)alloc((size_t)n * 4);
    int* rowptr = (int*)alloc((size_t)(n + 1) * 4);
    int* fill = (int*)alloc((size_t)n * 4);
    int* bsum = (int*)alloc((size_t)nb * 4);
    float* dinv = (float*)alloc((size_t)n * 4);
    int* csr_src = (int*)alloc((size_t)E * 4);
    float* csr_w = (float*)alloc((size_t)E * 4);
    unsigned short* Bp1 = (unsigned short*)alloc((size_t)(F_IN / 32) * L1W * 32 * 2);
    unsigned short* Bp2 = (unsigned short*)alloc((size_t)(L1W / 32) * L2WP * 32 * 2);
    unsigned short* Yb = (unsigned short*)alloc((size_t)n * L1W * 2);  // U (fp32 n*120) aliases
    unsigned short* Tz = (unsigned short*)alloc((size_t)n * 256 * 2);  // T2a/T2b (fp32) alias
    unsigned short* Xb = (unsigned short*)alloc((size_t)n * L1W * 2);  // Hb aliases Xb
    float* U = (float*)Yb;
    float* T2a = (float*)Tz;
    float* T2b = (float*)Tz + (size_t)n * C_OUT;
    unsigned short* Hb = Xb;
    (void)ws_size;

    // 0. edge dtype normalize
    detect_k<<<1, 256, 0, stream>>>(ei, flag);
    conv_k<<<(E + 255) / 256, 256, 0, stream>>>(ei, flag, srcN, dstN, E);

    // 1. CSR build
    hipMemsetAsync(cnt, 0, (size_t)n * 4, stream);
    hist_k<<<(E + 255) / 256, 256, 0, stream>>>(dstN, cnt, E);
    dinv_k<<<(n + 255) / 256, 256, 0, stream>>>(cnt, dinv, n);
    scan1_k<<<nb, 256, 0, stream>>>(cnt, bsum, n);
    scan2_k<<<1, 256, 0, stream>>>(bsum, rowptr + n, nb);
    scan3_k<<<nb, 256, 0, stream>>>(cnt, bsum, rowptr, fill, n);
    scatter_k<<<(E + 255) / 256, 256, 0, stream>>>(srcN, dstN, fill, csr_src, csr_w, dinv, E);

    // 2. bf16 conversions + weight packing
    cvt_bf_k<<<((n * F_IN / 4) + 255) / 256, 256, 0, stream>>>(x, Xb, n * F_IN / 4);
    pack1b_k<<<((F_IN / 32) * L1W * 32 + 255) / 256, 256, 0, stream>>>(W1_0, W1_1, W1_2, Bp1);
    pack2b_k<<<((L1W / 32) * L2WP * 32 + 255) / 256, 256, 0, stream>>>(W2_0, W2_1, W2_2, Bp2);

    // 3. layer 1: Yb = bf16(Xb @ Bp1)  [n x 384]
    {
        dim3 grid((n + 63) / 64, L1W / 64);
        mgemm_bf_k<<<grid, 256, 0, stream>>>(Xb, Bp1, Yb, n, F_IN, L1W, L1W);
    }
    // fused: Tz[:,0:128] = P(y1), Tz[:,128:256] = P(y2)
    prop256b_k<<<(n + 3) / 4, 256, 0, stream>>>(Yb, Tz, rowptr, csr_src, csr_w, dinv, n);
    // z2: Yb[:,256:384] = P(Tz[:,128:256])
    prop128b_k<<<(n + 3) / 4, 256, 0, stream>>>(Tz, Yb, rowptr, csr_src, csr_w, dinv, n);
    // h = relu(concat + b1) -> bf16 Hb
    bias_relu_bf_k<<<((n * L1W / 4) + 255) / 256, 256, 0, stream>>>(Yb, Tz, b1, Hb, n);

    // 4. layer 2: U = Hb @ Bp2  [n x 120]  (U aliases Yb; Yb dead)
    {
        dim3 grid((n + 63) / 64, L2WP / 64);
        mgemm_k<<<grid, 256, 0, stream>>>(Hb, Bp2, U, n, L1W, L2W, L2WP);
    }
    // fused: T2a = P(u1), T2b = P(u2)   (aliases Tz; Tz dead)
    prop80_k<<<(n + 3) / 4, 256, 0, stream>>>(U, T2a, T2b, rowptr, csr_src, csr_w, dinv, n);
    // v2 second hop: U[:,80:120] = P(T2b)
    prop40_k<<<(n + 3) / 4, 256, 0, stream>>>(T2b, C_OUT, 0, U, L2W, 80, rowptr, csr_src, csr_w, dinv, n);

    // 5. log_softmax epilogue
    lsm_k<<<(n + 3) / 4, 256, 0, stream>>>(U, T2a, b2, out, n);
}